// Round 2
// baseline (310.744 us; speedup 1.0000x reference)
//
#include <hip/hip_runtime.h>
#include <hip/hip_bf16.h>

#define B_ 16
#define T_ 16384
#define C_ 8
#define L_ 16384
#define W_ 256
#define R_ 32
#define NT_ 16   // tiles per block (persistent); 4 sub-blocks per (b,c)

typedef __bf16 bf16x8 __attribute__((ext_vector_type(8)));
typedef float f32x4 __attribute__((ext_vector_type(4)));

// ---------------------------------------------------------------------------
// Kernel 1: x (B,T,C) fp32  ->  xt (B,C,L) bf16
// ---------------------------------------------------------------------------
__global__ void xconv_kernel(const float* __restrict__ x,
                             unsigned short* __restrict__ xt) {
  unsigned idx = blockIdx.x * 256u + threadIdx.x;   // [0, B*C*L) = 2^21
  unsigned t = idx & (L_ - 1);
  unsigned c = (idx >> 14) & (C_ - 1);
  unsigned b = idx >> 17;
  float v = x[((size_t)b * T_ + t) * C_ + c];
  __bf16 h = (__bf16)v;   // RTNE
  xt[idx] = __builtin_bit_cast(unsigned short, h);
}

// ---------------------------------------------------------------------------
// Kernel 2: Gabor bank -> Fg[c][j][w] bf16, j in [0,64): j<32 real(r=j),
// j>=32 imag(r=j-32); param index = c*32 + (31 - r)  (bakes the [::-1])
// ---------------------------------------------------------------------------
__global__ void gen_filters_kernel(const float* __restrict__ kv,
                                   const float* __restrict__ sv,
                                   unsigned short* __restrict__ Fg) {
  unsigned idx = blockIdx.x * 256u + threadIdx.x;   // [0, 8*64*256)
  unsigned w = idx & (W_ - 1);
  unsigned j = (idx >> 8) & 63u;
  unsigned c = idx >> 14;
  unsigned r = j & 31u;
  unsigned pidx = c * 32u + (31u - r);
  float k  = kv[pidx];
  float sg = sv[pidx];
  float phase = (-6.283185307179586f / (float)W_) * k * (float)w;
  float dn = (float)w - (float)(W_ / 2);
  float var2 = 2.0f * sg * sg;                       // 2*sigma^2
  float g = (1.0f / sqrtf(3.14159265358979f * var2)) * expf(-(dn * dn) / var2);
  float s, cth;
  sincosf(phase, &s, &cth);
  float v = (j < 32u) ? cth * g : s * g;
  __bf16 h = (__bf16)v;
  Fg[idx] = __builtin_bit_cast(unsigned short, h);
}

// ---------------------------------------------------------------------------
// Kernel 3: persistent main MFMA kernel.
// Grid = 512 blocks (= 2/CU), block = 512 threads = 8 waves (4 wm x 2 wn).
// Block handles (b, c, sub): NT_=16 consecutive 256-row tiles; filters staged
// ONCE per block.  Per tile: MFMA phase reads atab[cur]; next tile's x-window
// global loads are issued BEFORE the MFMA phase (latency hidden under it);
// ds_write of the next window goes to atab[cur^1]; barrier; THEN the power
// epilogue stores are issued (so the barrier's vmcnt drain only ever waits
// on stores issued one full tile earlier).
//
// A is Toeplitz: A[t][k] = xwin[t+k].  atab entry e (16B) = xwin[e..e+7],
// stored at physical slot e ^ ((e>>3)&7)  (XOR swizzle: the read pattern
// e = base + {0,8,16,24,32} was a 5-way bank-group conflict unswizzled).
// Fragment p = mt + 2*kk -> rotating 4-slot register window, 18 loads/wave.
// ---------------------------------------------------------------------------
__global__ __launch_bounds__(512, 4) void wavelet_main_kernel(
    const unsigned short* __restrict__ xt,   // [B][C][L] bf16
    const unsigned short* __restrict__ Fg,   // [C][64][256] bf16
    float* __restrict__ out)                 // [B][L][256] fp32
{
  // 64 filter rows, 256 bf16 each, padded to 264 bf16 (132 dwords) per row
  __shared__ __align__(16) unsigned int Fs[64 * 132];   // 33792 B
  __shared__ __align__(16) uint4 atab[2 * 512];         // 16384 B (dbuf)

  const int tid = threadIdx.x;
  const unsigned bid = blockIdx.x;          // [0, 512)
  const int sub = bid & 3;                  // 4 sub-blocks per (b,c)
  const int c   = (bid >> 2) & 7;
  const int b   = bid >> 5;

  // ---- stage filters ONCE: 64x256 bf16 = 2048 uint4 ----
  {
    const uint4* Fg4 = reinterpret_cast<const uint4*>(Fg + (size_t)c * (64 * 256));
    #pragma unroll
    for (int it = 0; it < 4; ++it) {
      int i = it * 512 + tid;
      uint4 v = Fg4[i];
      int j  = i >> 5;              // 32 uint4 per 256-bf16 row
      int wq = (i & 31) << 2;       // dword offset within row
      *reinterpret_cast<uint4*>(&Fs[j * 132 + wq]) = v;
    }
  }

  const unsigned short* xrow = xt + ((size_t)b * C_ + c) * L_;
  const int sphys = tid ^ ((tid >> 3) & 7);   // swizzled entry slot for tid

  // guarded dword load of xrow[gi..gi+1] (gi even; whole dword in [0,L) or 0)
  auto ldx = [&](int gi) -> unsigned {
    return ((unsigned)gi <= (unsigned)(L_ - 2))
               ? *reinterpret_cast<const unsigned*>(xrow + gi) : 0u;
  };

  // ---- build atab[0] for first tile ----
  {
    const int g  = (sub * NT_) * 256 - 128 + tid;
    const int ga = g & ~1;
    unsigned d0 = ldx(ga), d1 = ldx(ga + 2), d2 = ldx(ga + 4),
             d3 = ldx(ga + 6), d4 = ldx(ga + 8);
    uint4 e;
    if (g & 1) {
      e.x = (d0 >> 16) | (d1 << 16);
      e.y = (d1 >> 16) | (d2 << 16);
      e.z = (d2 >> 16) | (d3 << 16);
      e.w = (d3 >> 16) | (d4 << 16);
    } else {
      e.x = d0; e.y = d1; e.z = d2; e.w = d3;
    }
    atab[sphys] = e;
  }
  __syncthreads();

  const int lane = tid & 63;
  const int wv   = tid >> 6;
  const int wm   = wv >> 1;          // row quarter: 64 rows each
  const int wn   = wv & 1;           // col half: 16 output cols each
  const int quad = lane >> 4;
  const int lrow = lane & 15;

  const int abase = wm * 64 + lrow + quad * 8;
  const unsigned int* fs0 = &Fs[(wn * 16 + lrow) * 132 + quad * 4];
  const unsigned int* fs1 = &Fs[(wn * 16 + lrow + 32) * 132 + quad * 4];
  const size_t obase = (size_t)b * ((size_t)L_ * 256)
                     + (size_t)(c * 32 + wn * 16 + lrow);

  int cur = 0;
  #pragma unroll 1
  for (int it = 0; it < NT_; ++it) {
    const int t0 = (sub * NT_ + it) * 256;
    const uint4* tb_ = atab + cur * 512;

    // ---- issue next tile's x-window loads NOW (hide HBM latency under MFMA)
    // (at it = NT_-1 this loads/writes a never-read buffer: harmless)
    const int gN  = t0 + 256 - 128 + tid;
    const int gaN = gN & ~1;
    unsigned nd0 = ldx(gaN), nd1 = ldx(gaN + 2), nd2 = ldx(gaN + 4),
             nd3 = ldx(gaN + 6), nd4 = ldx(gaN + 8);

    // ---- MFMA phase on atab[cur] ----
    f32x4 acc[4][2];
    #pragma unroll
    for (int mt = 0; mt < 4; ++mt) {
      acc[mt][0] = (f32x4){0.f, 0.f, 0.f, 0.f};
      acc[mt][1] = (f32x4){0.f, 0.f, 0.f, 0.f};
    }

    bf16x8 af[4];
    #pragma unroll
    for (int p = 0; p < 4; ++p) {
      const int e = abase + 16 * p;
      af[p] = __builtin_bit_cast(bf16x8, tb_[e ^ ((e >> 3) & 7)]);
    }

    #pragma unroll
    for (int kk = 0; kk < 8; ++kk) {
      if (kk) {
        const int e0 = abase + 16 * (2 * kk + 2);
        const int e1 = abase + 16 * (2 * kk + 3);
        af[(2 * kk + 2) & 3] = __builtin_bit_cast(bf16x8, tb_[e0 ^ ((e0 >> 3) & 7)]);
        af[(2 * kk + 3) & 3] = __builtin_bit_cast(bf16x8, tb_[e1 ^ ((e1 >> 3) & 7)]);
      }
      const bf16x8 bfr0 = __builtin_bit_cast(bf16x8,
          *reinterpret_cast<const uint4*>(fs0 + kk * 16));
      const bf16x8 bfr1 = __builtin_bit_cast(bf16x8,
          *reinterpret_cast<const uint4*>(fs1 + kk * 16));
      #pragma unroll
      for (int mt = 0; mt < 4; ++mt) {
        acc[mt][0] = __builtin_amdgcn_mfma_f32_16x16x32_bf16(
            af[(2 * kk + mt) & 3], bfr0, acc[mt][0], 0, 0, 0);
        acc[mt][1] = __builtin_amdgcn_mfma_f32_16x16x32_bf16(
            af[(2 * kk + mt) & 3], bfr1, acc[mt][1], 0, 0, 0);
      }
    }

    // ---- write next tile's window into the other buffer ----
    {
      uint4 e;
      if (gN & 1) {
        e.x = (nd0 >> 16) | (nd1 << 16);
        e.y = (nd1 >> 16) | (nd2 << 16);
        e.z = (nd2 >> 16) | (nd3 << 16);
        e.w = (nd3 >> 16) | (nd4 << 16);
      } else {
        e.x = nd0; e.y = nd1; e.z = nd2; e.w = nd3;
      }
      atab[(cur ^ 1) * 512 + sphys] = e;
    }
    __syncthreads();

    // ---- epilogue AFTER the barrier: stores drain under next tile's MFMA ----
    #pragma unroll
    for (int mt = 0; mt < 4; ++mt) {
      #pragma unroll
      for (int i = 0; i < 4; ++i) {
        const int t = t0 + wm * 64 + mt * 16 + quad * 4 + i;
        __builtin_nontemporal_store(
            acc[mt][0][i] * acc[mt][0][i] + acc[mt][1][i] * acc[mt][1][i],
            out + obase + (size_t)t * 256);
      }
    }
    cur ^= 1;
  }
}

// ---------------------------------------------------------------------------
extern "C" void kernel_launch(void* const* d_in, const int* in_sizes, int n_in,
                              void* d_out, int out_size, void* d_ws, size_t ws_size,
                              hipStream_t stream) {
  const float* x  = (const float*)d_in[0];
  const float* kv = (const float*)d_in[1];
  const float* sv = (const float*)d_in[2];
  float* out = (float*)d_out;

  unsigned short* xt = (unsigned short*)d_ws;                 // B*C*L bf16 = 4 MB
  unsigned short* Fg = xt + (size_t)B_ * C_ * L_;             // 8*64*256 bf16 = 256 KB

  hipLaunchKernelGGL(xconv_kernel, dim3((B_ * C_ * L_) / 256), dim3(256), 0, stream,
                     x, xt);
  hipLaunchKernelGGL(gen_filters_kernel, dim3((C_ * 64 * W_) / 256), dim3(256), 0, stream,
                     kv, sv, Fg);
  hipLaunchKernelGGL(wavelet_main_kernel, dim3(B_ * C_ * 4), dim3(512), 0, stream,
                     xt, Fg, out);
}

// Round 3
// 287.145 us; speedup vs baseline: 1.0822x; 1.0822x over previous
//
#include <hip/hip_runtime.h>
#include <hip/hip_bf16.h>

#define B_ 16
#define T_ 16384
#define C_ 8
#define L_ 16384
#define W_ 256
#define R_ 32

typedef __bf16 bf16x8 __attribute__((ext_vector_type(8)));
typedef float f32x4 __attribute__((ext_vector_type(4)));

// ---------------------------------------------------------------------------
// Kernel 1: Gabor bank -> Fg[c][j][w] bf16, j in [0,64): j<32 real(r=j),
// j>=32 imag(r=j-32); param index = c*32 + (31 - r)  (bakes the [::-1])
// ---------------------------------------------------------------------------
__global__ void gen_filters_kernel(const float* __restrict__ kv,
                                   const float* __restrict__ sv,
                                   unsigned short* __restrict__ Fg) {
  unsigned idx = blockIdx.x * 256u + threadIdx.x;   // [0, 8*64*256)
  unsigned w = idx & (W_ - 1);
  unsigned j = (idx >> 8) & 63u;
  unsigned c = idx >> 14;
  unsigned r = j & 31u;
  unsigned pidx = c * 32u + (31u - r);
  float k  = kv[pidx];
  float sg = sv[pidx];
  float phase = (-6.283185307179586f / (float)W_) * k * (float)w;
  float dn = (float)w - (float)(W_ / 2);
  float var2 = 2.0f * sg * sg;                       // 2*sigma^2
  float g = (1.0f / sqrtf(3.14159265358979f * var2)) * expf(-(dn * dn) / var2);
  float s, cth;
  sincosf(phase, &s, &cth);
  float v = (j < 32u) ? cth * g : s * g;
  __bf16 h = (__bf16)v;
  Fg[idx] = __builtin_bit_cast(unsigned short, h);
}

// ---------------------------------------------------------------------------
// Kernel 2: main MFMA kernel (round-1 structure + fused x->bf16 conversion).
// Block = 256 threads = 4 waves (2 wm x 2 wn), handles (b, c, 256 t-rows).
// Wave (wm,wn): rows [wm*128, wm*128+128) x output cols [wn*16, wn*16+16),
// real (filter rows wn*16+lrow) and imag (+32) in acc[mt][0] / acc[mt][1].
//
// x is read DIRECTLY (fp32, stride C) -- no xconv pre-pass.  Phase 0 stages
// xs16[d] = pack(bf16(xwin[2d]), bf16(xwin[2d+1])) to LDS (2 guarded scalar
// loads/thread; x is L3-resident).  Phase 1 builds the Toeplitz table
// atab[s] = xwin[s..s+7] (16B entry) from xs16, so every A fragment is ONE
// aligned ds_read_b128 at base + 256*(mt + 2*kk).  Fragments shared along
// diagonals p = mt + 2*kk -> rotating 8-slot register window.
// ---------------------------------------------------------------------------
__global__ __launch_bounds__(256, 2) void wavelet_main_kernel(
    const float* __restrict__ x,             // [B][T][C] fp32
    const unsigned short* __restrict__ Fg,   // [C][64][256] bf16
    float* __restrict__ out)                 // [B][L][256] fp32
{
  // 64 filter rows, 256 bf16 each, padded to 264 bf16 (132 dwords) per row
  __shared__ __align__(16) unsigned int Fs[64 * 132];   // 33792 B
  __shared__ __align__(16) uint4 atab[512];             // 8192 B
  __shared__ unsigned int xs16[264];                    // packed bf16 window

  const int tid = threadIdx.x;
  const unsigned bid = blockIdx.x;
  const int tb = bid & 63;           // 64 t-blocks per (b,c)
  const int c  = (bid >> 6) & 7;
  const int b  = bid >> 9;
  const int t0 = tb << 8;            // 256 t per block

  // ---- phase 0a: x window -> packed bf16 in LDS ----
  // xwin[i] = bf16(x[b, t0-128+i, c]), zero outside [0, L)
  {
    const float* xb = x + (size_t)b * (T_ * C_) + c;
    const int ta = t0 - 128 + 2 * tid;
    float f0 = ((unsigned)ta       < (unsigned)L_) ? xb[ta * C_]       : 0.f;
    float f1 = ((unsigned)(ta + 1) < (unsigned)L_) ? xb[(ta + 1) * C_] : 0.f;
    const unsigned h0 = (unsigned)__builtin_bit_cast(unsigned short, (__bf16)f0);
    const unsigned h1 = (unsigned)__builtin_bit_cast(unsigned short, (__bf16)f1);
    xs16[tid] = h0 | (h1 << 16);
    if (tid < 8) xs16[256 + tid] = 0u;   // tail pad (entries >= 504 are unused)
  }

  // ---- phase 0b: stage filters: 64x256 bf16 = 2048 uint4 ----
  {
    const uint4* Fg4 = reinterpret_cast<const uint4*>(Fg + (size_t)c * (64 * 256));
    #pragma unroll
    for (int it = 0; it < 8; ++it) {
      int i = it * 256 + tid;
      uint4 v = Fg4[i];
      int j  = i >> 5;              // 32 uint4 per 256-bf16 row
      int wq = (i & 31) << 2;       // dword offset within row
      *reinterpret_cast<uint4*>(&Fs[j * 132 + wq]) = v;
    }
  }
  __syncthreads();

  // ---- phase 1: build atab[2*tid], atab[2*tid+1] from xs16[tid..tid+4] ----
  {
    const unsigned d0 = xs16[tid];
    const unsigned d1 = xs16[tid + 1];
    const unsigned d2 = xs16[tid + 2];
    const unsigned d3 = xs16[tid + 3];
    const unsigned d4 = xs16[tid + 4];
    uint4 ev;  // entry s = 2*tid   : xwin[2t .. 2t+7]
    ev.x = d0; ev.y = d1; ev.z = d2; ev.w = d3;
    uint4 od;  // entry s = 2*tid+1 : xwin[2t+1 .. 2t+8]
    od.x = (d0 >> 16) | (d1 << 16);
    od.y = (d1 >> 16) | (d2 << 16);
    od.z = (d2 >> 16) | (d3 << 16);
    od.w = (d3 >> 16) | (d4 << 16);
    atab[2 * tid]     = ev;
    atab[2 * tid + 1] = od;
  }
  __syncthreads();

  const int lane = tid & 63;
  const int wv   = tid >> 6;
  const int wm   = wv >> 1;          // row half: 0 or 1 (128 rows each)
  const int wn   = wv & 1;           // col half: 0 or 1 (16 output cols each)
  const int quad = lane >> 4;
  const int lrow = lane & 15;

  // A fragment base: entry index (wm*128 + lrow + quad*8); fragment p adds 16*p
  const uint4* tabp = atab + (wm * 128 + lrow + quad * 8);
  // B fragment bases: filter row wn*16+lrow (real) and +32 (imag)
  const unsigned int* fs0 = &Fs[(wn * 16 + lrow) * 132 + quad * 4];
  const unsigned int* fs1 = &Fs[(wn * 16 + lrow + 32) * 132 + quad * 4];

  f32x4 acc[8][2];
  #pragma unroll
  for (int mt = 0; mt < 8; ++mt) {
    acc[mt][0] = (f32x4){0.f, 0.f, 0.f, 0.f};
    acc[mt][1] = (f32x4){0.f, 0.f, 0.f, 0.f};
  }

  // rotating window of A fragments: slot (p & 7) holds diagonal p
  bf16x8 af[8];
  #pragma unroll
  for (int p = 0; p < 8; ++p)
    af[p] = __builtin_bit_cast(bf16x8, tabp[16 * p]);

  #pragma unroll
  for (int kk = 0; kk < 8; ++kk) {
    if (kk) {
      af[(2 * kk + 6) & 7] = __builtin_bit_cast(bf16x8, tabp[16 * (2 * kk + 6)]);
      af[(2 * kk + 7) & 7] = __builtin_bit_cast(bf16x8, tabp[16 * (2 * kk + 7)]);
    }
    const bf16x8 bfr0 = __builtin_bit_cast(bf16x8,
        *reinterpret_cast<const uint4*>(fs0 + kk * 16));
    const bf16x8 bfr1 = __builtin_bit_cast(bf16x8,
        *reinterpret_cast<const uint4*>(fs1 + kk * 16));
    #pragma unroll
    for (int mt = 0; mt < 8; ++mt) {
      acc[mt][0] = __builtin_amdgcn_mfma_f32_16x16x32_bf16(
          af[(2 * kk + mt) & 7], bfr0, acc[mt][0], 0, 0, 0);
      acc[mt][1] = __builtin_amdgcn_mfma_f32_16x16x32_bf16(
          af[(2 * kk + mt) & 7], bfr1, acc[mt][1], 0, 0, 0);
    }
  }

  // ---- epilogue: power = real^2 + imag^2 ----
  // D layout: row = quad*4 + i, col = lrow (per 16x16 tile).
  // Output col = c*32 + wn*16 + lrow; one float per (mt,i).
  const size_t obase = (size_t)b * ((size_t)L_ * 256)
                     + (size_t)(c * 32 + wn * 16 + lrow);
  #pragma unroll
  for (int mt = 0; mt < 8; ++mt) {
    #pragma unroll
    for (int i = 0; i < 4; ++i) {
      const int t = t0 + wm * 128 + mt * 16 + quad * 4 + i;
      out[obase + (size_t)t * 256] =
          acc[mt][0][i] * acc[mt][0][i] + acc[mt][1][i] * acc[mt][1][i];
    }
  }
}

// ---------------------------------------------------------------------------
extern "C" void kernel_launch(void* const* d_in, const int* in_sizes, int n_in,
                              void* d_out, int out_size, void* d_ws, size_t ws_size,
                              hipStream_t stream) {
  const float* x  = (const float*)d_in[0];
  const float* kv = (const float*)d_in[1];
  const float* sv = (const float*)d_in[2];
  float* out = (float*)d_out;

  unsigned short* Fg = (unsigned short*)d_ws;   // 8*64*256 bf16 = 256 KB

  hipLaunchKernelGGL(gen_filters_kernel, dim3((C_ * 64 * W_) / 256), dim3(256), 0, stream,
                     kv, sv, Fg);
  hipLaunchKernelGGL(wavelet_main_kernel, dim3(B_ * C_ * 64), dim3(256), 0, stream,
                     x, Fg, out);
}